// Round 1
// baseline (160.021 us; speedup 1.0000x reference)
//
#include <hip/hip_runtime.h>
#include <math.h>

typedef unsigned short u16;
typedef unsigned int u32;
typedef __attribute__((ext_vector_type(4))) float f32x4;
typedef __attribute__((ext_vector_type(8))) short s16x8;
typedef __attribute__((ext_vector_type(4))) unsigned short u16x4;

#define T_ 2048
#define C_ 1024

// fp32 -> bf16, round-half-up (max err 0.5 ulp, values always finite here)
__device__ __forceinline__ u16 f2b(float f) {
  u32 u = __builtin_bit_cast(u32, f);
  return (u16)((u + 0x8000u) >> 16);
}

// ---------------- kernel 0: weights fp32 [1024][64] x3 -> Wt bf16 [192][1024]
// transposed (k-contiguous). Softmax scale 1/8 folded into W_q.
__global__ __launch_bounds__(256) void wconv(const float* __restrict__ Wq,
                                             const float* __restrict__ Wk,
                                             const float* __restrict__ Wv,
                                             u16* __restrict__ Wt) {
  int n = blockIdx.x;  // 0..191
  const float* src;
  float scale = 1.0f;
  if (n < 64) { src = Wq; scale = 0.125f; }
  else if (n < 128) { src = Wk; }
  else { src = Wv; }
  int col = n & 63;
  for (int kk = threadIdx.x; kk < C_; kk += 256)
    Wt[(size_t)n * C_ + kk] = f2b(src[(size_t)kk * 64 + col] * scale);
}

// ---------------- kernel 1: qkv projection, bf16 MFMA
// x [16384][1024] fp32 @ Wt^T -> q,k [16384][64] bf16 row-major; v transposed
// vT [8][64][2048] bf16. 256 blocks of 64 rows; BK=64; reg-prefetch staging.
__global__ __launch_bounds__(256) void proj(const float* __restrict__ x,
                                            const u16* __restrict__ Wt,
                                            u16* __restrict__ qo,
                                            u16* __restrict__ ko,
                                            u16* __restrict__ vt) {
  __shared__ __align__(16) u16 xs[64 * 72];    // x tile, stride 72 (pad)
  __shared__ __align__(16) u16 ws[192 * 72];   // Wt tile
  const int tid = threadIdx.x;
  const int wave = tid >> 6, lane = tid & 63;
  const int quad = lane >> 4, l15 = lane & 15;
  const int m0 = blockIdx.x * 64;

  f32x4 acc[4][3];
#pragma unroll
  for (int m = 0; m < 4; ++m)
#pragma unroll
    for (int j = 0; j < 3; ++j) acc[m][j] = {0.f, 0.f, 0.f, 0.f};

  const int xrow = tid >> 4;        // 0..15, +16 per iter
  const int xc4 = (tid & 15) * 4;
  const int wrow = tid >> 3;        // 0..31, +32 per iter
  const int wc8 = (tid & 7) * 8;

  float4 xr[4];
  uint4 wr[6];
#pragma unroll
  for (int i = 0; i < 4; ++i)
    xr[i] = *(const float4*)(x + (size_t)(m0 + xrow + i * 16) * C_ + xc4);
#pragma unroll
  for (int i = 0; i < 6; ++i)
    wr[i] = *(const uint4*)(Wt + (size_t)(wrow + i * 32) * C_ + wc8);

  for (int kt = 0; kt < 16; ++kt) {
#pragma unroll
    for (int i = 0; i < 4; ++i) {
      u16x4 pk = {f2b(xr[i].x), f2b(xr[i].y), f2b(xr[i].z), f2b(xr[i].w)};
      *(u16x4*)(&xs[(xrow + i * 16) * 72 + xc4]) = pk;
    }
#pragma unroll
    for (int i = 0; i < 6; ++i)
      *(uint4*)(&ws[(wrow + i * 32) * 72 + wc8]) = wr[i];
    __syncthreads();
    if (kt < 15) {  // prefetch next K-tile; overlaps MFMA below
      const int k1 = (kt + 1) * 64;
#pragma unroll
      for (int i = 0; i < 4; ++i)
        xr[i] = *(const float4*)(x + (size_t)(m0 + xrow + i * 16) * C_ + k1 + xc4);
#pragma unroll
      for (int i = 0; i < 6; ++i)
        wr[i] = *(const uint4*)(Wt + (size_t)(wrow + i * 32) * C_ + k1 + wc8);
    }
#pragma unroll
    for (int ks = 0; ks < 2; ++ks) {
      s16x8 a[4], bfr[3];
#pragma unroll
      for (int m = 0; m < 4; ++m)
        a[m] = *(const s16x8*)(&xs[(l15 + 16 * m) * 72 + ks * 32 + quad * 8]);
#pragma unroll
      for (int j = 0; j < 3; ++j)
        bfr[j] = *(const s16x8*)(&ws[(l15 + 16 * (wave * 3 + j)) * 72 + ks * 32 + quad * 8]);
#pragma unroll
      for (int m = 0; m < 4; ++m)
#pragma unroll
        for (int j = 0; j < 3; ++j)
          acc[m][j] = __builtin_amdgcn_mfma_f32_16x16x32_bf16(a[m], bfr[j], acc[m][j], 0, 0, 0);
    }
    __syncthreads();
  }
  // epilogue: C layout col=lane&15, row=quad*4+i (per 16x16 subtile)
#pragma unroll
  for (int m = 0; m < 4; ++m) {
    int rbase = m0 + 16 * m + quad * 4;
#pragma unroll
    for (int j = 0; j < 3; ++j) {
      int ns = wave * 3 + j;
      if (ns < 4) {
        int col = ns * 16 + l15;
#pragma unroll
        for (int i = 0; i < 4; ++i)
          qo[(size_t)(rbase + i) * 64 + col] = f2b(acc[m][j][i]);
      } else if (ns < 8) {
        int col = (ns - 4) * 16 + l15;
#pragma unroll
        for (int i = 0; i < 4; ++i)
          ko[(size_t)(rbase + i) * 64 + col] = f2b(acc[m][j][i]);
      } else {
        int d = (ns - 8) * 16 + l15;
        int bb = m0 >> 11;
        int t0 = (m0 & 2047) + 16 * m + quad * 4;  // 4 consecutive t -> pack
        u16x4 pk = {f2b(acc[m][j][0]), f2b(acc[m][j][1]),
                    f2b(acc[m][j][2]), f2b(acc[m][j][3])};
        *(u16x4*)(vt + (size_t)bb * (64 * T_) + (size_t)d * T_ + t0) = pk;
      }
    }
  }
}

// ---------------- kernel 2: causal flash attention
// block = (q-tile of 64, batch); 4 waves; wave w owns kv-tiles j = w, w+4, ...
// with private online-softmax state; partials merged at the end via LDS.
// Computes S^T = K·Q^T so q-index sits in lane&15 (2-shuffle row reductions,
// packed P stores); PV as O^T = V^T·P^T (all frag reads contiguous).
__global__ __launch_bounds__(256, 1) void attn(const u16* __restrict__ qw,
                                               const u16* __restrict__ kw,
                                               const u16* __restrict__ vt,
                                               float* __restrict__ out) {
  __shared__ __align__(16) u16 Pb[4 * 64 * 72];  // per-wave P; reused for O
  __shared__ float mbuf[4][64];
  __shared__ float lbuf[4][64];
  const int tid = threadIdx.x;
  const int wave = tid >> 6, lane = tid & 63;
  const int quad = lane >> 4, l15 = lane & 15;
  const int qt = blockIdx.x, b = blockIdx.y;

  const u16* qp = qw + ((size_t)b * T_ + qt * 64) * 64;
  const u16* kb = kw + (size_t)b * T_ * 64;
  const u16* vb = vt + (size_t)b * 64 * T_;

  s16x8 qf[4][2];  // Q as B-operand: qf[nsub_q][kstep]
#pragma unroll
  for (int n = 0; n < 4; ++n)
#pragma unroll
    for (int ks = 0; ks < 2; ++ks)
      qf[n][ks] = *(const s16x8*)(qp + (16 * n + l15) * 64 + ks * 32 + quad * 8);

  f32x4 o[4][4];  // O^T accumulator: o[msub_d][nsub_q]
  float mr[4], lr[4];
#pragma unroll
  for (int m = 0; m < 4; ++m)
#pragma unroll
    for (int n = 0; n < 4; ++n) o[m][n] = {0.f, 0.f, 0.f, 0.f};
#pragma unroll
  for (int n = 0; n < 4; ++n) { mr[n] = -INFINITY; lr[n] = 0.0f; }

  u16* P = Pb + wave * (64 * 72);

  for (int j = wave; j <= qt; j += 4) {
    const u16* kp = kb + (size_t)j * 64 * 64;
    const u16* vp = vb + j * 64;
    f32x4 s[4][4];  // S^T: s[msub_kv][nsub_q]
#pragma unroll
    for (int m = 0; m < 4; ++m)
#pragma unroll
      for (int n = 0; n < 4; ++n) s[m][n] = {0.f, 0.f, 0.f, 0.f};
#pragma unroll
    for (int ks = 0; ks < 2; ++ks) {
      s16x8 kf[4];
#pragma unroll
      for (int m = 0; m < 4; ++m)
        kf[m] = *(const s16x8*)(kp + (16 * m + l15) * 64 + ks * 32 + quad * 8);
#pragma unroll
      for (int m = 0; m < 4; ++m)
#pragma unroll
        for (int n = 0; n < 4; ++n)
          s[m][n] = __builtin_amdgcn_mfma_f32_16x16x32_bf16(kf[m], qf[n][ks], s[m][n], 0, 0, 0);
    }
    if (j == qt) {  // diagonal tile: kv col c = 16m+quad*4+i, q row r = 16n+l15
#pragma unroll
      for (int m = 0; m < 4; ++m)
#pragma unroll
        for (int n = 0; n < 4; ++n)
#pragma unroll
          for (int i = 0; i < 4; ++i)
            if (16 * m + quad * 4 + i > 16 * n + l15) s[m][n][i] = -INFINITY;
    }
    float al[4];
#pragma unroll
    for (int n = 0; n < 4; ++n) {
      float mt = s[0][n][0];
#pragma unroll
      for (int m = 0; m < 4; ++m)
#pragma unroll
        for (int i = 0; i < 4; ++i) mt = fmaxf(mt, s[m][n][i]);
      mt = fmaxf(mt, __shfl_xor(mt, 16));
      mt = fmaxf(mt, __shfl_xor(mt, 32));
      float mn = fmaxf(mr[n], mt);
      al[n] = __expf(mr[n] - mn);  // exp(-inf)=0 on first tile
      mr[n] = mn;
      float rs = 0.0f;
#pragma unroll
      for (int m = 0; m < 4; ++m)
#pragma unroll
        for (int i = 0; i < 4; ++i) {
          float p = __expf(s[m][n][i] - mn);
          s[m][n][i] = p;
          rs += p;
        }
      rs += __shfl_xor(rs, 16);
      rs += __shfl_xor(rs, 32);
      lr[n] = lr[n] * al[n] + rs;
    }
    // P -> LDS row-major [q][kv] (stride 72), packed 8B stores (wave-private)
#pragma unroll
    for (int n = 0; n < 4; ++n)
#pragma unroll
      for (int m = 0; m < 4; ++m) {
        u16x4 pk = {f2b(s[m][n][0]), f2b(s[m][n][1]), f2b(s[m][n][2]), f2b(s[m][n][3])};
        *(u16x4*)(&P[(16 * n + l15) * 72 + 16 * m + quad * 4]) = pk;
      }
#pragma unroll
    for (int m = 0; m < 4; ++m)
#pragma unroll
      for (int n = 0; n < 4; ++n) o[m][n] *= al[n];
    // O^T += V^T (A, global L2) · P^T (B, LDS contiguous reads of P rows)
#pragma unroll
    for (int ks = 0; ks < 2; ++ks) {
      s16x8 vf[4], pf[4];
#pragma unroll
      for (int m = 0; m < 4; ++m)
        vf[m] = *(const s16x8*)(vp + (size_t)(16 * m + l15) * T_ + ks * 32 + quad * 8);
#pragma unroll
      for (int n = 0; n < 4; ++n)
        pf[n] = *(const s16x8*)(&P[(16 * n + l15) * 72 + ks * 32 + quad * 8]);
#pragma unroll
      for (int m = 0; m < 4; ++m)
#pragma unroll
        for (int n = 0; n < 4; ++n)
          o[m][n] = __builtin_amdgcn_mfma_f32_16x16x32_bf16(vf[m], pf[n], o[m][n], 0, 0, 0);
    }
  }
  // per-wave stats (value replicated across quads after xor16/32 reduce)
  if (quad == 0) {
#pragma unroll
    for (int n = 0; n < 4; ++n) {
      mbuf[wave][16 * n + l15] = mr[n];
      lbuf[wave][16 * n + l15] = lr[n];
    }
  }
  __syncthreads();  // all waves done with their P region before O reuse
  // O^T -> LDS as [q][d] bf16 over Pb, packed (i indexes consecutive d)
#pragma unroll
  for (int m = 0; m < 4; ++m)
#pragma unroll
    for (int n = 0; n < 4; ++n) {
      u16x4 pk = {f2b(o[m][n][0]), f2b(o[m][n][1]), f2b(o[m][n][2]), f2b(o[m][n][3])};
      *(u16x4*)(&Pb[wave * (64 * 72) + (16 * n + l15) * 72 + 16 * m + quad * 4]) = pk;
    }
  __syncthreads();
  // merge 4 wave-partials: lane handles q-row r, d-chunk cg
  const int r = wave * 16 + (lane >> 2);
  const int cg = (lane & 3) * 16;
  float fw[4];
  float mstar = -INFINITY, lsum = 0.0f;
#pragma unroll
  for (int w = 0; w < 4; ++w) mstar = fmaxf(mstar, mbuf[w][r]);
#pragma unroll
  for (int w = 0; w < 4; ++w) {
    fw[w] = __expf(mbuf[w][r] - mstar);
    lsum += fw[w] * lbuf[w][r];
  }
  const float inv = 1.0f / lsum;
  float accv[16];
#pragma unroll
  for (int e = 0; e < 16; ++e) accv[e] = 0.0f;
#pragma unroll
  for (int w = 0; w < 4; ++w) {
#pragma unroll
    for (int h = 0; h < 2; ++h) {
      s16x8 vv = *(const s16x8*)(&Pb[w * (64 * 72) + r * 72 + cg + h * 8]);
#pragma unroll
      for (int e = 0; e < 8; ++e) {
        float f = __builtin_bit_cast(float, ((u32)(u16)vv[e]) << 16);
        accv[h * 8 + e] += fw[w] * f;
      }
    }
  }
  float* op = out + ((size_t)b * T_ + qt * 64 + r) * 64 + cg;
#pragma unroll
  for (int e = 0; e < 16; e += 4) {
    float4 st = {accv[e] * inv, accv[e + 1] * inv, accv[e + 2] * inv, accv[e + 3] * inv};
    *(float4*)(op + e) = st;
  }
}

extern "C" void kernel_launch(void* const* d_in, const int* in_sizes, int n_in,
                              void* d_out, int out_size, void* d_ws, size_t ws_size,
                              hipStream_t stream) {
  const float* x  = (const float*)d_in[0];
  const float* Wq = (const float*)d_in[1];
  const float* Wk = (const float*)d_in[2];
  const float* Wv = (const float*)d_in[3];
  float* out = (float*)d_out;
  char* ws = (char*)d_ws;
  u16* Wt = (u16*)ws;                                   // 192*1024*2 = 384 KB
  u16* q  = (u16*)(ws + 393216);                        // 2 MB
  u16* k  = (u16*)(ws + 393216 + 2097152);              // 2 MB
  u16* vT = (u16*)(ws + 393216 + 2 * 2097152);          // 2 MB
  hipLaunchKernelGGL(wconv, dim3(192), dim3(256), 0, stream, Wq, Wk, Wv, Wt);
  hipLaunchKernelGGL(proj, dim3(256), dim3(256), 0, stream, x, Wt, q, k, vT);
  hipLaunchKernelGGL(attn, dim3(32, 8), dim3(256), 0, stream, q, k, vT, out);
}